// Round 7
// baseline (359.711 us; speedup 1.0000x reference)
//
#include <hip/hip_runtime.h>
#include <hip/hip_bf16.h>

typedef _Float16 half8 __attribute__((ext_vector_type(8)));
typedef _Float16 half4 __attribute__((ext_vector_type(4)));
typedef float floatx4 __attribute__((ext_vector_type(4)));
typedef float floatx16 __attribute__((ext_vector_type(16)));

#define EMBED 1024
#define SEQ   2048
#define BATCH 32
#define M_TOT (BATCH * SEQ)   // 65536 rows
#define KDIM  1024
#define NDIM  1024

// async global->LDS, 16B per lane, dest = wave-uniform base + lane*16
#define GLOAD16(g, l) __builtin_amdgcn_global_load_lds(                      \
    (const __attribute__((address_space(1))) void*)(g),                      \
    (__attribute__((address_space(3))) void*)(l), 16, 0, 0)

// ---------------------------------------------------------------------------
// Kernel 1: transpose + convert W[K][N] fp32 -> Wt[N][K] fp16
// ---------------------------------------------------------------------------
__global__ void transpose_w_kernel(const float* __restrict__ W,
                                   _Float16* __restrict__ Wt) {
    __shared__ float t[32][33];
    const int kt = blockIdx.x * 32;
    const int nt = blockIdx.y * 32;
    #pragma unroll
    for (int i = 0; i < 4; ++i)
        t[threadIdx.y + 8 * i][threadIdx.x] =
            W[(size_t)(kt + threadIdx.y + 8 * i) * NDIM + nt + threadIdx.x];
    __syncthreads();
    #pragma unroll
    for (int i = 0; i < 4; ++i)
        Wt[(size_t)(nt + threadIdx.y + 8 * i) * KDIM + kt + threadIdx.x] =
            (_Float16)t[threadIdx.x][threadIdx.y + 8 * i];
}

// ---------------------------------------------------------------------------
// Kernel 2: zero scores + out
// ---------------------------------------------------------------------------
__global__ void zero_kernel(float* __restrict__ scores, float* __restrict__ out) {
    const int i = blockIdx.x * 256 + threadIdx.x;
    if (i < M_TOT) scores[i] = 0.0f;
    if (i < BATCH * EMBED) out[i] = 0.0f;
}

// ---------------------------------------------------------------------------
// Kernel 3: fused scores GEMM. BM=128, BN=256, BK=32, 512 threads (8 waves,
// 2M x 4N, wave-tile 64x64 via 2x2 mfma_f32_32x32x16_f16 frags).
// A staged as FP32 via gload_lds (no separate cvt pass; fp32->fp16 at
// frag-load, VALU was idle), B fp16.  One __syncthreads per K-tile
// (r4-proven), gload_lds(16B), both-sides XOR slot swizzle:
//   A rows = 32 f32 = 8x16B slots, physical p = s ^ (row&7)
//   B rows = 32 f16 = 4x16B slots, physical p = s ^ (row&3)
// staged by pre-swizzling the GLOBAL source slot, LDS dest linear (m173).
// XCD chunk swizzle: contiguous bm range per XCD.
// ---------------------------------------------------------------------------
__global__ __launch_bounds__(512, 4) void score_gemm6(
    const float* __restrict__ x, const _Float16* __restrict__ Wt,
    const float* __restrict__ bias, const float* __restrict__ ctx,
    float* __restrict__ scores) {
    __shared__ float    As[2][128 * 32];   // 16 KB per buf
    __shared__ _Float16 Bs[2][256 * 32];   // 16 KB per buf  (total 64 KB)

    const int tid  = threadIdx.x;
    const int lane = tid & 63;
    const int w    = tid >> 6;    // 0..7
    const int wm   = w >> 2;      // 0..1  (64-row group)
    const int wn   = w & 3;       // 0..3  (64-col group)

    // grid 2048 = 512 bm x 4 bn; XCD chunk swizzle (bijective: 8 x 256)
    const int nb = ((blockIdx.x & 7) << 8) | (blockIdx.x >> 3);
    const int bm = nb >> 2;
    const int bn = nb & 3;

    // ---- staging geometry ----
    // A (fp32): instr i in {0,1}: rows i*64 + w*8 + (l>>3); 16B slot l&7 linear
    //           in LDS; global slot g = (l&7) ^ (l>>3)   (row&7 == l>>3)
    const int arow = lane >> 3;                // 0..7
    const int agsl = (lane & 7) ^ arow;        // pre-swizzled global slot
    // B (fp16): instr i: rows i*128 + w*16 + (l>>2); slot l&3 linear;
    //           global slot g = (l&3) ^ ((l>>2)&3)
    const int brow = lane >> 2;                // 0..15
    const int bgsl = (lane & 3) ^ (brow & 3);

    const float*    Ab = x  + (size_t)(bm * 128) * KDIM;
    const _Float16* Bb = Wt + (size_t)(bn * 256) * KDIM;
    const size_t aoff = (size_t)(w * 8 + arow) * KDIM + agsl * 4;   // floats
    const size_t boff = (size_t)(w * 16 + brow) * KDIM + bgsl * 8;  // halves

    #define STAGE(buf, kt)                                                       \
        {                                                                        \
            _Pragma("unroll")                                                    \
            for (int i = 0; i < 2; ++i)                                          \
                GLOAD16(Ab + aoff + (size_t)i * 64 * KDIM + (kt) * 32,           \
                        &As[buf][(i * 64 + w * 8) * 32]);                        \
            _Pragma("unroll")                                                    \
            for (int i = 0; i < 2; ++i)                                          \
                GLOAD16(Bb + boff + (size_t)i * 128 * KDIM + (kt) * 32,          \
                        &Bs[buf][(i * 128 + w * 16) * 32]);                      \
        }

    // ---- frag read geometry (32x32x16: lane row = l&31, k = (l>>5)*8 + j) ----
    const int fr32 = lane & 31;
    const int fhi  = lane >> 5;     // 0..1
    const int ax   = lane & 7;      // A row&7
    const int bx   = lane & 3;      // B row&3

    floatx16 acc[2][2] = {};

    STAGE(0, 0);
    __syncthreads();

    for (int kt = 0; kt < KDIM / 32; ++kt) {
        const int cur = kt & 1;
        if (kt + 1 < KDIM / 32) STAGE(cur ^ 1, kt + 1);   // lands during compute

        #pragma unroll
        for (int ks = 0; ks < 2; ++ks) {
            // B frags: one b128 each; logical slot s = ks*2 + fhi, phys s^ (row&3)
            half8 bf[2];
            #pragma unroll
            for (int nf = 0; nf < 2; ++nf) {
                const int r = wn * 64 + nf * 32 + fr32;
                bf[nf] = *(const half8*)&Bs[cur][r * 32 + (((ks * 2 + fhi) ^ bx) * 8)];
            }
            // A frags: two b128 fp32 + pack to fp16; slots s0=ks*4+fhi*2, s0+1
            half8 af[2];
            #pragma unroll
            for (int mf = 0; mf < 2; ++mf) {
                const int r  = wm * 64 + mf * 32 + fr32;
                const int s0 = ks * 4 + fhi * 2;
                const floatx4 f0 = *(const floatx4*)&As[cur][r * 32 + ((s0 ^ ax) * 4)];
                const floatx4 f1 = *(const floatx4*)&As[cur][r * 32 + (((s0 + 1) ^ ax) * 4)];
                half8 a;
                a[0] = (_Float16)f0[0]; a[1] = (_Float16)f0[1];
                a[2] = (_Float16)f0[2]; a[3] = (_Float16)f0[3];
                a[4] = (_Float16)f1[0]; a[5] = (_Float16)f1[1];
                a[6] = (_Float16)f1[2]; a[7] = (_Float16)f1[3];
                af[mf] = a;
            }
            #pragma unroll
            for (int mf = 0; mf < 2; ++mf)
                #pragma unroll
                for (int nf = 0; nf < 2; ++nf)
                    acc[mf][nf] = __builtin_amdgcn_mfma_f32_32x32x16_f16(
                        af[mf], bf[nf], acc[mf][nf], 0, 0, 0);
        }
        __syncthreads();   // reads of buf cur done; next STAGE may overwrite it
    }
    #undef STAGE

    // ---- epilogue: fast tanh + ctx dot + 32-lane reduce + atomic ----
    // C/D 32x32 layout: col = lane&31, row = (reg&3) + 8*(reg>>2) + 4*(lane>>5)
    const int c0 = bn * 256 + wn * 64 + fr32;
    const float bv0 = bias[c0],      cv0 = ctx[c0];
    const float bv1 = bias[c0 + 32], cv1 = ctx[c0 + 32];

    #pragma unroll
    for (int mf = 0; mf < 2; ++mf) {
        #pragma unroll
        for (int reg = 0; reg < 16; ++reg) {
            const float v0 = acc[mf][0][reg] + bv0;
            const float v1 = acc[mf][1][reg] + bv1;
            // tanh(v) = 1 - 2/(e^{2v}+1); exact at both saturations
            const float t0 = 1.0f - 2.0f * __builtin_amdgcn_rcpf(__expf(2.0f * v0) + 1.0f);
            const float t1 = 1.0f - 2.0f * __builtin_amdgcn_rcpf(__expf(2.0f * v1) + 1.0f);
            float partial = t0 * cv0 + t1 * cv1;
            #pragma unroll
            for (int off = 1; off < 32; off <<= 1)
                partial += __shfl_xor(partial, off, 64);   // stays in 32-lane half
            if (fr32 == 0) {
                const int row = bm * 128 + wm * 64 + mf * 32 +
                                (reg & 3) + 8 * (reg >> 2) + 4 * fhi;
                atomicAdd(&scores[row], partial);
            }
        }
    }
}

// ---------------------------------------------------------------------------
// Kernel 4: softmax over seq dim per batch. 32 blocks x 256 threads.
// ---------------------------------------------------------------------------
__global__ void softmax_kernel(const float* __restrict__ scores,
                               float* __restrict__ weights) {
    const int bb = blockIdx.x;
    const int tid = threadIdx.x;
    const float* s = scores + (size_t)bb * SEQ;
    float* w = weights + (size_t)bb * SEQ;

    __shared__ float red[8];

    float v[8];
    float mx = -1e30f;
    #pragma unroll
    for (int i = 0; i < 8; ++i) {
        v[i] = s[tid + i * 256];
        mx = fmaxf(mx, v[i]);
    }
    #pragma unroll
    for (int off = 1; off < 64; off <<= 1)
        mx = fmaxf(mx, __shfl_xor(mx, off, 64));
    const int wv = tid >> 6;
    if ((tid & 63) == 0) red[wv] = mx;
    __syncthreads();
    mx = fmaxf(fmaxf(red[0], red[1]), fmaxf(red[2], red[3]));

    float sum = 0.0f;
    #pragma unroll
    for (int i = 0; i < 8; ++i) {
        v[i] = __expf(v[i] - mx);
        sum += v[i];
    }
    #pragma unroll
    for (int off = 1; off < 64; off <<= 1)
        sum += __shfl_xor(sum, off, 64);
    if ((tid & 63) == 0) red[4 + wv] = sum;
    __syncthreads();
    sum = red[4] + red[5] + red[6] + red[7];
    const float inv = 1.0f / sum;
    #pragma unroll
    for (int i = 0; i < 8; ++i)
        w[tid + i * 256] = v[i] * inv;
}

// ---------------------------------------------------------------------------
// Kernel 5: weighted pooling (fp32 x). out[b,e] = sum_s w[b,s] * x[b,s,e]
// ---------------------------------------------------------------------------
__global__ __launch_bounds__(256) void pool_kernel(const float* __restrict__ x,
                                                   const float* __restrict__ weights,
                                                   float* __restrict__ out) {
    const int bb = blockIdx.x >> 4;
    const int sc = blockIdx.x & 15;
    const int tid = threadIdx.x;

    const float4* xb = (const float4*)(x + (size_t)bb * SEQ * EMBED) +
                       (size_t)(sc * 128) * (EMBED / 4) + tid;
    const float* wb = weights + (size_t)bb * SEQ + sc * 128;

    float ax = 0.f, ay = 0.f, az = 0.f, aw = 0.f;
    #pragma unroll 4
    for (int s = 0; s < 128; ++s) {
        const float wgt = wb[s];
        const float4 xv = xb[(size_t)s * (EMBED / 4)];
        ax += wgt * xv.x; ay += wgt * xv.y; az += wgt * xv.z; aw += wgt * xv.w;
    }
    float* o = out + (size_t)bb * EMBED + tid * 4;
    atomicAdd(o + 0, ax);
    atomicAdd(o + 1, ay);
    atomicAdd(o + 2, az);
    atomicAdd(o + 3, aw);
}

// ---------------------------------------------------------------------------
extern "C" void kernel_launch(void* const* d_in, const int* in_sizes, int n_in,
                              void* d_out, int out_size, void* d_ws, size_t ws_size,
                              hipStream_t stream) {
    const float* x   = (const float*)d_in[0];
    const float* W   = (const float*)d_in[1];
    const float* b   = (const float*)d_in[2];
    const float* ctx = (const float*)d_in[3];
    float* out = (float*)d_out;

    char* ws = (char*)d_ws;
    _Float16* Wt      = (_Float16*)ws;                               // 2 MB
    float*    scores  = (float*)(ws + (2u << 20));                   // 256 KB
    float*    weights = (float*)(ws + (2u << 20) + (256u << 10));    // 256 KB

    hipLaunchKernelGGL(transpose_w_kernel, dim3(32, 32), dim3(32, 8), 0, stream, W, Wt);
    hipLaunchKernelGGL(zero_kernel, dim3(M_TOT / 256), dim3(256), 0, stream, scores, out);
    hipLaunchKernelGGL(score_gemm6, dim3(2048), dim3(512), 0, stream,
                       x, Wt, b, ctx, scores);
    hipLaunchKernelGGL(softmax_kernel, dim3(BATCH), dim3(256), 0, stream, scores, weights);
    hipLaunchKernelGGL(pool_kernel, dim3(BATCH * 16), dim3(256), 0, stream,
                       x, weights, out);
}

// Round 9
// 306.565 us; speedup vs baseline: 1.1734x; 1.1734x over previous
//
#include <hip/hip_runtime.h>
#include <hip/hip_bf16.h>

typedef _Float16 half8 __attribute__((ext_vector_type(8)));
typedef _Float16 half4 __attribute__((ext_vector_type(4)));
typedef float floatx4 __attribute__((ext_vector_type(4)));

#define EMBED 1024
#define SEQ   2048
#define BATCH 32
#define M_TOT (BATCH * SEQ)   // 65536 rows
#define KDIM  1024
#define NDIM  1024

// async global->LDS, 16B per lane, dest = wave-uniform base + lane*16
#define GLOAD16(g, l) __builtin_amdgcn_global_load_lds(                      \
    (const __attribute__((address_space(1))) void*)(g),                      \
    (__attribute__((address_space(3))) void*)(l), 16, 0, 0)

// ---------------------------------------------------------------------------
// Kernel 1: transpose + convert W[K][N] fp32 -> Wt[N][K] fp16
// ---------------------------------------------------------------------------
__global__ void transpose_w_kernel(const float* __restrict__ W,
                                   _Float16* __restrict__ Wt) {
    __shared__ float t[32][33];
    const int kt = blockIdx.x * 32;
    const int nt = blockIdx.y * 32;
    #pragma unroll
    for (int i = 0; i < 4; ++i)
        t[threadIdx.y + 8 * i][threadIdx.x] =
            W[(size_t)(kt + threadIdx.y + 8 * i) * NDIM + nt + threadIdx.x];
    __syncthreads();
    #pragma unroll
    for (int i = 0; i < 4; ++i)
        Wt[(size_t)(nt + threadIdx.y + 8 * i) * KDIM + kt + threadIdx.x] =
            (_Float16)t[threadIdx.x][threadIdx.y + 8 * i];
}

// ---------------------------------------------------------------------------
// Kernel 2: zero scores + out
// ---------------------------------------------------------------------------
__global__ void zero_kernel(float* __restrict__ scores, float* __restrict__ out) {
    const int i = blockIdx.x * 256 + threadIdx.x;
    if (i < M_TOT) scores[i] = 0.0f;
    if (i < BATCH * EMBED) out[i] = 0.0f;
}

// ---------------------------------------------------------------------------
// Kernel 2b: convert x fp32 -> fp16 (64M elements)
// ---------------------------------------------------------------------------
__global__ __launch_bounds__(256) void cvt_x_kernel(const float* __restrict__ x,
                                                    _Float16* __restrict__ x16) {
    const size_t stride = (size_t)gridDim.x * 256 * 8;
    for (size_t i = ((size_t)blockIdx.x * 256 + threadIdx.x) * 8;
         i < (size_t)M_TOT * KDIM; i += stride) {
        const float4 a = *(const float4*)(x + i);
        const float4 b = *(const float4*)(x + i + 4);
        half8 h;
        h[0] = (_Float16)a.x; h[1] = (_Float16)a.y; h[2] = (_Float16)a.z; h[3] = (_Float16)a.w;
        h[4] = (_Float16)b.x; h[5] = (_Float16)b.y; h[6] = (_Float16)b.z; h[7] = (_Float16)b.w;
        *(half8*)(x16 + i) = h;
    }
}

// ---------------------------------------------------------------------------
// Kernel 3: fused scores GEMM — r4 structure + DEPTH-2 PREFETCH RING.
// BM=128, BN=128, BK=32, 256 threads (2x2 waves, 64x64 wave-tile),
// mfma_f32_16x16x32_f16, gload_lds(16B), r4's verified slot swizzle.
// LDS ring of 3 tile-buffers (48 KB -> 3 blocks/CU); stage-ahead = 2 K-tiles;
// raw s_barrier (no compiler vmcnt(0) drain) + manual s_waitcnt vmcnt(8):
// own in-flight = 8 loads (tiles kt+1, kt+2), so waiting to 8 completes tile
// kt for THIS wave; the barrier then makes it complete block-wide.
// Ring safety: STAGE(kt+2) overwrites the slot last read at tile kt-1; the
// second barrier (after compute) orders those reads before the overwrite.
// ---------------------------------------------------------------------------
__global__ __launch_bounds__(256, 3) void score_gemm7(
    const _Float16* __restrict__ x16, const _Float16* __restrict__ Wt,
    const float* __restrict__ bias, const float* __restrict__ ctx,
    float* __restrict__ scores) {
    __shared__ _Float16 As[3][128 * 32];
    __shared__ _Float16 Bs[3][128 * 32];

    // XCD-aware chunk swizzle (4096 blocks, 8 XCDs, bijective)
    const int nb = ((blockIdx.x & 7) << 9) | (blockIdx.x >> 3);
    const int bm = nb >> 3;       // 512 row tiles, contiguous per XCD
    const int bn = nb & 7;        // 8 col tiles, innermost per XCD
    const int tid = threadIdx.x;
    const int lane = tid & 63;
    const int wid = tid >> 6;
    const int wm = wid >> 1;
    const int wn = wid & 1;

    // staging geometry (r4-verified): instr j covers rows j*16..j*16+15;
    // lane l -> row j*16 + (l>>2), 16B slot l&3 linear in LDS; global slot
    // pre-swizzled s = (l&3) ^ ((l>>2)&3).
    const int jA0 = wid * 2;                    // 2 A-instrs + 2 B-instrs per wave
    const int lrow = lane >> 2;                 // 0..15
    const int gslot = (lane & 3) ^ (lrow & 3);  // pre-swizzled global 16B slot
    const int gcol = gslot * 8;                 // halves

    const _Float16* Ab = x16 + (size_t)(bm * 128) * KDIM;
    const _Float16* Bb = Wt  + (size_t)(bn * 128) * KDIM;

    floatx4 acc[4][4] = {};

    // frag read addresses (r4-verified swizzle)
    const int fslot = ((lane >> 4) ^ (lane & 3)) * 8;   // halves
    const int frow = lane & 15;

    #define STAGE(buf, kt)                                                        \
        {                                                                         \
            const int kc = (kt) * 32 + gcol;                                      \
            _Pragma("unroll")                                                     \
            for (int i = 0; i < 2; ++i) {                                         \
                const int j = jA0 + i;                                            \
                GLOAD16(Ab + (size_t)(j * 16 + lrow) * KDIM + kc, &As[buf][j * 512]); \
                GLOAD16(Bb + (size_t)(j * 16 + lrow) * KDIM + kc, &Bs[buf][j * 512]); \
            }                                                                     \
        }

    #define COMPUTE(buf)                                                          \
        {                                                                         \
            half8 afr[4], bfr[4];                                                 \
            _Pragma("unroll")                                                     \
            for (int m = 0; m < 4; ++m)                                           \
                afr[m] = *(const half8*)&As[buf][(wm * 64 + m * 16 + frow) * 32 + fslot]; \
            _Pragma("unroll")                                                     \
            for (int n = 0; n < 4; ++n)                                           \
                bfr[n] = *(const half8*)&Bs[buf][(wn * 64 + n * 16 + frow) * 32 + fslot]; \
            __builtin_amdgcn_s_setprio(1);                                        \
            _Pragma("unroll")                                                     \
            for (int m = 0; m < 4; ++m)                                           \
                _Pragma("unroll")                                                 \
                for (int n = 0; n < 4; ++n)                                       \
                    acc[m][n] = __builtin_amdgcn_mfma_f32_16x16x32_f16(           \
                        afr[m], bfr[n], acc[m][n], 0, 0, 0);                      \
            __builtin_amdgcn_s_setprio(0);                                        \
        }

    // prologue: stage tiles 0 and 1 (8 loads in flight)
    STAGE(0, 0);
    STAGE(1, 1);

    int cur = 0;        // buffer of tile kt
    int stg = 2;        // buffer of tile kt+2
    for (int kt = 0; kt < KDIM / 32 - 2; ++kt) {
        STAGE(stg, kt + 2);                              // 12 in flight
        asm volatile("s_waitcnt vmcnt(8)" ::: "memory"); // own tile-kt loads done
        __builtin_amdgcn_s_barrier();                    // block-wide: tile kt ready
        COMPUTE(cur);
        __builtin_amdgcn_s_barrier();                    // reads done; slot reusable
        cur = (cur == 2) ? 0 : cur + 1;
        stg = (stg == 2) ? 0 : stg + 1;
    }
    // kt = 30: no stage; 8 in flight (tiles 30,31) -> wait to 4 completes 30
    asm volatile("s_waitcnt vmcnt(4)" ::: "memory");
    __builtin_amdgcn_s_barrier();
    COMPUTE(cur);
    __builtin_amdgcn_s_barrier();
    cur = (cur == 2) ? 0 : cur + 1;
    // kt = 31: drain all
    asm volatile("s_waitcnt vmcnt(0)" ::: "memory");
    __builtin_amdgcn_s_barrier();
    COMPUTE(cur);

    #undef COMPUTE
    #undef STAGE

    // ---- epilogue: fast tanh + ctx dot + 16-lane reduce + atomic ----
    float bv[4], cv[4];
    #pragma unroll
    for (int n = 0; n < 4; ++n) {
        const int col = bn * 128 + wn * 64 + n * 16 + (lane & 15);
        bv[n] = bias[col];
        cv[n] = ctx[col];
    }
    #pragma unroll
    for (int m = 0; m < 4; ++m) {
        #pragma unroll
        for (int j = 0; j < 4; ++j) {
            float partial = 0.0f;
            #pragma unroll
            for (int n = 0; n < 4; ++n) {
                const float v = acc[m][n][j] + bv[n];
                const float e = __expf(2.0f * v);          // tanh(v)=1-2/(e^{2v}+1)
                const float t = 1.0f - 2.0f * __builtin_amdgcn_rcpf(e + 1.0f);
                partial += t * cv[n];
            }
            #pragma unroll
            for (int off = 1; off < 16; off <<= 1)
                partial += __shfl_xor(partial, off, 64);
            if ((lane & 15) == 0) {
                const int rowg = bm * 128 + wm * 64 + m * 16 + (lane >> 4) * 4 + j;
                atomicAdd(&scores[rowg], partial);
            }
        }
    }
}

// ---------------------------------------------------------------------------
// Fallback GEMM (ws too small for x16): reg-staged fp32 path.
// ---------------------------------------------------------------------------
__global__ __launch_bounds__(256) void score_gemm_f32(
    const float* __restrict__ A32p, const _Float16* __restrict__ Wt,
    const float* __restrict__ bias, const float* __restrict__ ctx,
    float* __restrict__ scores) {
    __shared__ _Float16 As[128 * 64];
    __shared__ _Float16 Bs[128 * 64];

    const int bid = blockIdx.x;
    const int bm = bid >> 3;
    const int bn = bid & 7;
    const int tid = threadIdx.x;
    const int lane = tid & 63;
    const int wid = tid >> 6;
    const int wm = wid >> 1;
    const int wn = wid & 1;

    const int c = tid & 7;
    const int r0 = tid >> 3;
    const int swz = (r0 & 7) << 3;
    const int wcol = (c * 8) ^ swz;

    float4 aF[4][2];
    int4   bR[4];

    #pragma unroll
    for (int i = 0; i < 4; ++i) {
        const int row = r0 + 32 * i;
        const float* p = A32p + (size_t)(bm * 128 + row) * KDIM + c * 8;
        aF[i][0] = *(const float4*)p;
        aF[i][1] = *(const float4*)(p + 4);
        bR[i] = *(const int4*)(Wt + (size_t)(bn * 128 + row) * KDIM + c * 8);
    }

    floatx4 acc[4][4] = {};

    for (int kt = 0; kt < KDIM / 64; ++kt) {
        __syncthreads();
        #pragma unroll
        for (int i = 0; i < 4; ++i) {
            const int row = r0 + 32 * i;
            half8 h;
            h[0] = (_Float16)aF[i][0].x; h[1] = (_Float16)aF[i][0].y;
            h[2] = (_Float16)aF[i][0].z; h[3] = (_Float16)aF[i][0].w;
            h[4] = (_Float16)aF[i][1].x; h[5] = (_Float16)aF[i][1].y;
            h[6] = (_Float16)aF[i][1].z; h[7] = (_Float16)aF[i][1].w;
            *(half8*)&As[row * 64 + wcol] = h;
            *(int4*)&Bs[row * 64 + wcol] = bR[i];
        }
        __syncthreads();

        if (kt + 1 < KDIM / 64) {
            #pragma unroll
            for (int i = 0; i < 4; ++i) {
                const int row = r0 + 32 * i;
                const float* p = A32p + (size_t)(bm * 128 + row) * KDIM + (kt + 1) * 64 + c * 8;
                aF[i][0] = *(const float4*)p;
                aF[i][1] = *(const float4*)(p + 4);
                bR[i] = *(const int4*)(Wt + (size_t)(bn * 128 + row) * KDIM + (kt + 1) * 64 + c * 8);
            }
        }

        #pragma unroll
        for (int s = 0; s < 2; ++s) {
            half8 afr[4], bfr[4];
            const int colr = s * 32 + (lane >> 4) * 8;
            #pragma unroll
            for (int m = 0; m < 4; ++m) {
                const int row = wm * 64 + m * 16 + (lane & 15);
                afr[m] = *(const half8*)&As[row * 64 + (colr ^ ((row & 7) << 3))];
            }
            #pragma unroll
            for (int n = 0; n < 4; ++n) {
                const int row = wn * 64 + n * 16 + (lane & 15);
                bfr[n] = *(const half8*)&Bs[row * 64 + (colr ^ ((row & 7) << 3))];
            }
            #pragma unroll
            for (int m = 0; m < 4; ++m)
                #pragma unroll
                for (int n = 0; n < 4; ++n)
                    acc[m][n] = __builtin_amdgcn_mfma_f32_16x16x32_f16(
                        afr[m], bfr[n], acc[m][n], 0, 0, 0);
        }
    }

    float bv[4], cv[4];
    #pragma unroll
    for (int n = 0; n < 4; ++n) {
        const int col = bn * 128 + wn * 64 + n * 16 + (lane & 15);
        bv[n] = bias[col];
        cv[n] = ctx[col];
    }
    #pragma unroll
    for (int m = 0; m < 4; ++m) {
        #pragma unroll
        for (int j = 0; j < 4; ++j) {
            float partial = 0.0f;
            #pragma unroll
            for (int n = 0; n < 4; ++n) {
                const float v = acc[m][n][j] + bv[n];
                const float e = __expf(2.0f * v);
                const float t = 1.0f - 2.0f * __builtin_amdgcn_rcpf(e + 1.0f);
                partial += t * cv[n];
            }
            #pragma unroll
            for (int off = 1; off < 16; off <<= 1)
                partial += __shfl_xor(partial, off, 64);
            if ((lane & 15) == 0) {
                const int rowg = bm * 128 + wm * 64 + m * 16 + (lane >> 4) * 4 + j;
                atomicAdd(&scores[rowg], partial);
            }
        }
    }
}

// ---------------------------------------------------------------------------
// Kernel 4: softmax over seq dim per batch. 32 blocks x 256 threads.
// ---------------------------------------------------------------------------
__global__ void softmax_kernel(const float* __restrict__ scores,
                               float* __restrict__ weights) {
    const int bb = blockIdx.x;
    const int tid = threadIdx.x;
    const float* s = scores + (size_t)bb * SEQ;
    float* w = weights + (size_t)bb * SEQ;

    __shared__ float red[8];

    float v[8];
    float mx = -1e30f;
    #pragma unroll
    for (int i = 0; i < 8; ++i) {
        v[i] = s[tid + i * 256];
        mx = fmaxf(mx, v[i]);
    }
    #pragma unroll
    for (int off = 1; off < 64; off <<= 1)
        mx = fmaxf(mx, __shfl_xor(mx, off, 64));
    const int wv = tid >> 6;
    if ((tid & 63) == 0) red[wv] = mx;
    __syncthreads();
    mx = fmaxf(fmaxf(red[0], red[1]), fmaxf(red[2], red[3]));

    float sum = 0.0f;
    #pragma unroll
    for (int i = 0; i < 8; ++i) {
        v[i] = __expf(v[i] - mx);
        sum += v[i];
    }
    #pragma unroll
    for (int off = 1; off < 64; off <<= 1)
        sum += __shfl_xor(sum, off, 64);
    if ((tid & 63) == 0) red[4 + wv] = sum;
    __syncthreads();
    sum = red[4] + red[5] + red[6] + red[7];
    const float inv = 1.0f / sum;
    #pragma unroll
    for (int i = 0; i < 8; ++i)
        w[tid + i * 256] = v[i] * inv;
}

// ---------------------------------------------------------------------------
// Kernel 5: weighted pooling (fp32 fallback).
// ---------------------------------------------------------------------------
__global__ __launch_bounds__(256) void pool_kernel(const float* __restrict__ x,
                                                   const float* __restrict__ weights,
                                                   float* __restrict__ out) {
    const int bb = blockIdx.x >> 4;
    const int sc = blockIdx.x & 15;
    const int tid = threadIdx.x;

    const float4* xb = (const float4*)(x + (size_t)bb * SEQ * EMBED) +
                       (size_t)(sc * 128) * (EMBED / 4) + tid;
    const float* wb = weights + (size_t)bb * SEQ + sc * 128;

    float ax = 0.f, ay = 0.f, az = 0.f, aw = 0.f;
    #pragma unroll 4
    for (int s = 0; s < 128; ++s) {
        const float wgt = wb[s];
        const float4 xv = xb[(size_t)s * (EMBED / 4)];
        ax += wgt * xv.x; ay += wgt * xv.y; az += wgt * xv.z; aw += wgt * xv.w;
    }
    float* o = out + (size_t)bb * EMBED + tid * 4;
    atomicAdd(o + 0, ax);
    atomicAdd(o + 1, ay);
    atomicAdd(o + 2, az);
    atomicAdd(o + 3, aw);
}

// ---------------------------------------------------------------------------
// Kernel 5b: weighted pooling (fp16 x16) — halves the read bytes.
// ---------------------------------------------------------------------------
__global__ __launch_bounds__(256) void pool16_kernel(const _Float16* __restrict__ x16,
                                                     const float* __restrict__ weights,
                                                     float* __restrict__ out) {
    const int bb = blockIdx.x >> 4;
    const int sc = blockIdx.x & 15;
    const int tid = threadIdx.x;

    const _Float16* xb = x16 + (size_t)bb * SEQ * EMBED +
                         (size_t)(sc * 128) * EMBED + tid * 4;
    const float* wb = weights + (size_t)bb * SEQ + sc * 128;

    float ax = 0.f, ay = 0.f, az = 0.f, aw = 0.f;
    #pragma unroll 4
    for (int s = 0; s < 128; ++s) {
        const float wgt = wb[s];
        const half4 h = *(const half4*)(xb + (size_t)s * EMBED);
        ax += wgt * (float)h[0]; ay += wgt * (float)h[1];
        az += wgt * (float)h[2]; aw += wgt * (float)h[3];
    }
    float* o = out + (size_t)bb * EMBED + tid * 4;
    atomicAdd(o + 0, ax);
    atomicAdd(o + 1, ay);
    atomicAdd(o + 2, az);
    atomicAdd(o + 3, aw);
}

// ---------------------------------------------------------------------------
extern "C" void kernel_launch(void* const* d_in, const int* in_sizes, int n_in,
                              void* d_out, int out_size, void* d_ws, size_t ws_size,
                              hipStream_t stream) {
    const float* x   = (const float*)d_in[0];
    const float* W   = (const float*)d_in[1];
    const float* b   = (const float*)d_in[2];
    const float* ctx = (const float*)d_in[3];
    float* out = (float*)d_out;

    char* ws = (char*)d_ws;
    _Float16* Wt      = (_Float16*)ws;                               // 2 MB
    float*    scores  = (float*)(ws + (2u << 20));                   // 256 KB
    float*    weights = (float*)(ws + (2u << 20) + (256u << 10));    // 256 KB
    _Float16* x16     = (_Float16*)(ws + (4u << 20));                // 128 MB

    const size_t need = (4ull << 20) + ((size_t)M_TOT * KDIM * 2);
    const bool fast = ws_size >= need;

    hipLaunchKernelGGL(transpose_w_kernel, dim3(32, 32), dim3(32, 8), 0, stream, W, Wt);
    hipLaunchKernelGGL(zero_kernel, dim3(M_TOT / 256), dim3(256), 0, stream, scores, out);

    if (fast) {
        hipLaunchKernelGGL(cvt_x_kernel, dim3(4096), dim3(256), 0, stream, x, x16);
        hipLaunchKernelGGL(score_gemm7, dim3(4096), dim3(256), 0, stream,
                           x16, Wt, b, ctx, scores);
    } else {
        hipLaunchKernelGGL(score_gemm_f32, dim3(4096), dim3(256), 0, stream,
                           x, Wt, b, ctx, scores);
    }

    hipLaunchKernelGGL(softmax_kernel, dim3(BATCH), dim3(256), 0, stream, scores, weights);

    if (fast) {
        hipLaunchKernelGGL(pool16_kernel, dim3(BATCH * 16), dim3(256), 0, stream,
                           x16, weights, out);
    } else {
        hipLaunchKernelGGL(pool_kernel, dim3(BATCH * 16), dim3(256), 0, stream,
                           x, weights, out);
    }
}

// Round 10
// 289.632 us; speedup vs baseline: 1.2420x; 1.0585x over previous
//
#include <hip/hip_runtime.h>
#include <hip/hip_bf16.h>

typedef _Float16 half8 __attribute__((ext_vector_type(8)));
typedef _Float16 half4 __attribute__((ext_vector_type(4)));
typedef float floatx4 __attribute__((ext_vector_type(4)));

#define EMBED 1024
#define SEQ   2048
#define BATCH 32
#define M_TOT (BATCH * SEQ)   // 65536 rows
#define KDIM  1024
#define NDIM  1024

// async global->LDS, 16B per lane, dest = wave-uniform base + lane*16
#define GLOAD16(g, l) __builtin_amdgcn_global_load_lds(                      \
    (const __attribute__((address_space(1))) void*)(g),                      \
    (__attribute__((address_space(3))) void*)(l), 16, 0, 0)

// ---------------------------------------------------------------------------
// Kernel 1: transpose + convert W[K][N] fp32 -> Wt[N][K] fp16
// ---------------------------------------------------------------------------
__global__ void transpose_w_kernel(const float* __restrict__ W,
                                   _Float16* __restrict__ Wt) {
    __shared__ float t[32][33];
    const int kt = blockIdx.x * 32;
    const int nt = blockIdx.y * 32;
    #pragma unroll
    for (int i = 0; i < 4; ++i)
        t[threadIdx.y + 8 * i][threadIdx.x] =
            W[(size_t)(kt + threadIdx.y + 8 * i) * NDIM + nt + threadIdx.x];
    __syncthreads();
    #pragma unroll
    for (int i = 0; i < 4; ++i)
        Wt[(size_t)(nt + threadIdx.y + 8 * i) * KDIM + kt + threadIdx.x] =
            (_Float16)t[threadIdx.x][threadIdx.y + 8 * i];
}

// ---------------------------------------------------------------------------
// Kernel 2: zero scores + out
// ---------------------------------------------------------------------------
__global__ void zero_kernel(float* __restrict__ scores, float* __restrict__ out) {
    const int i = blockIdx.x * 256 + threadIdx.x;
    if (i < M_TOT) scores[i] = 0.0f;
    if (i < BATCH * EMBED) out[i] = 0.0f;
}

// ---------------------------------------------------------------------------
// Kernel 2b: convert x fp32 -> fp16 (64M elements)
// ---------------------------------------------------------------------------
__global__ __launch_bounds__(256) void cvt_x_kernel(const float* __restrict__ x,
                                                    _Float16* __restrict__ x16) {
    const size_t stride = (size_t)gridDim.x * 256 * 8;
    for (size_t i = ((size_t)blockIdx.x * 256 + threadIdx.x) * 8;
         i < (size_t)M_TOT * KDIM; i += stride) {
        const float4 a = *(const float4*)(x + i);
        const float4 b = *(const float4*)(x + i + 4);
        half8 h;
        h[0] = (_Float16)a.x; h[1] = (_Float16)a.y; h[2] = (_Float16)a.z; h[3] = (_Float16)a.w;
        h[4] = (_Float16)b.x; h[5] = (_Float16)b.y; h[6] = (_Float16)b.z; h[7] = (_Float16)b.w;
        *(half8*)(x16 + i) = h;
    }
}

// ---------------------------------------------------------------------------
// Kernel 3: fused scores GEMM — r4 structure with CORRECTED bank swizzle.
// BM=128, BN=128, BK=32, 256 threads (2x2 waves, 64x64 wave-tile),
// mfma_f32_16x16x32_f16, gload_lds(16B), double-buffered LDS, one
// __syncthreads per K-step (best measured structure: 210 us r4).
//
// Bank analysis (64B rows = 16 words; banks wrap every 2 rows): the frag
// read pattern (16 rows x stride 64B, 16B/lane) needs XOR key (row>>1)&3 —
// r4's (row&3) key repeats with period 4 and left lanes l,l+4,l+8,l+12 on
// one bank (4-way, SQ_LDS_BANK_CONFLICT=1.7e7). With p = s ^ ((row>>1)&3)
// every 8-lane issue group covers banks 0..31 exactly once (conflict-free).
// Staged via pre-swizzled GLOBAL source slot g = (l&3) ^ ((l>>3)&3), LDS
// dest linear (both-sides involution, m173 / rule 21).
// ---------------------------------------------------------------------------
__global__ __launch_bounds__(256, 4) void score_gemm8(
    const _Float16* __restrict__ x16, const _Float16* __restrict__ Wt,
    const float* __restrict__ bias, const float* __restrict__ ctx,
    float* __restrict__ scores) {
    __shared__ _Float16 As[2][128 * 32];
    __shared__ _Float16 Bs[2][128 * 32];

    // XCD-aware chunk swizzle (4096 blocks, 8 XCDs, bijective)
    const int nb = ((blockIdx.x & 7) << 9) | (blockIdx.x >> 3);
    const int bm = nb >> 3;       // 512 row tiles, contiguous per XCD
    const int bn = nb & 7;        // 8 col tiles, innermost per XCD
    const int tid = threadIdx.x;
    const int lane = tid & 63;
    const int wid = tid >> 6;
    const int wm = wid >> 1;
    const int wn = wid & 1;

    // staging geometry: instr j covers rows j*16..j*16+15 (1 KB of LDS);
    // lane l -> row j*16 + (l>>2), LDS slot l&3 (linear dest);
    // global 16B slot pre-swizzled: g = (l&3) ^ ((l>>3)&3)  [= (row>>1)&3]
    const int jA0 = wid * 2;                        // 2 A-instrs + 2 B-instrs per wave
    const int lrow = lane >> 2;                     // 0..15
    const int gslot = (lane & 3) ^ ((lane >> 3) & 3);
    const int gcol = gslot * 8;                     // halves

    const _Float16* Ab = x16 + (size_t)(bm * 128) * KDIM;
    const _Float16* Bb = Wt  + (size_t)(bn * 128) * KDIM;

    floatx4 acc[4][4] = {};

    // frag read: row = base + frow, logical slot s = lane>>4,
    // physical p = s ^ ((row>>1)&3) = s ^ ((frow>>1)&3)
    const int frow = lane & 15;
    const int fslot = ((lane >> 4) ^ ((frow >> 1) & 3)) * 8;   // halves

    #define STAGE(buf, kt)                                                        \
        {                                                                         \
            const int kc = (kt) * 32 + gcol;                                      \
            _Pragma("unroll")                                                     \
            for (int i = 0; i < 2; ++i) {                                         \
                const int j = jA0 + i;                                            \
                GLOAD16(Ab + (size_t)(j * 16 + lrow) * KDIM + kc, &As[buf][j * 512]); \
                GLOAD16(Bb + (size_t)(j * 16 + lrow) * KDIM + kc, &Bs[buf][j * 512]); \
            }                                                                     \
        }

    STAGE(0, 0);
    __syncthreads();   // drains vmcnt(0): buf0 ready

    for (int kt = 0; kt < KDIM / 32; ++kt) {
        const int cur = kt & 1;
        if (kt + 1 < KDIM / 32) STAGE(cur ^ 1, kt + 1);   // in flight under compute

        half8 afr[4], bfr[4];
        #pragma unroll
        for (int m = 0; m < 4; ++m)
            afr[m] = *(const half8*)&As[cur][(wm * 64 + m * 16 + frow) * 32 + fslot];
        #pragma unroll
        for (int n = 0; n < 4; ++n)
            bfr[n] = *(const half8*)&Bs[cur][(wn * 64 + n * 16 + frow) * 32 + fslot];

        #pragma unroll
        for (int m = 0; m < 4; ++m)
            #pragma unroll
            for (int n = 0; n < 4; ++n)
                acc[m][n] = __builtin_amdgcn_mfma_f32_16x16x32_f16(
                    afr[m], bfr[n], acc[m][n], 0, 0, 0);

        __syncthreads();   // drains this iter's STAGE (vmcnt) + all ds reads
    }
    #undef STAGE

    // ---- epilogue: fast tanh + ctx dot + 16-lane reduce + atomic ----
    float bv[4], cv[4];
    #pragma unroll
    for (int n = 0; n < 4; ++n) {
        const int col = bn * 128 + wn * 64 + n * 16 + (lane & 15);
        bv[n] = bias[col];
        cv[n] = ctx[col];
    }
    #pragma unroll
    for (int m = 0; m < 4; ++m) {
        #pragma unroll
        for (int j = 0; j < 4; ++j) {
            float partial = 0.0f;
            #pragma unroll
            for (int n = 0; n < 4; ++n) {
                const float v = acc[m][n][j] + bv[n];
                const float e = __expf(2.0f * v);          // tanh(v)=1-2/(e^{2v}+1)
                const float t = 1.0f - 2.0f * __builtin_amdgcn_rcpf(e + 1.0f);
                partial += t * cv[n];
            }
            #pragma unroll
            for (int off = 1; off < 16; off <<= 1)
                partial += __shfl_xor(partial, off, 64);
            if ((lane & 15) == 0) {
                const int rowg = bm * 128 + wm * 64 + m * 16 + (lane >> 4) * 4 + j;
                atomicAdd(&scores[rowg], partial);
            }
        }
    }
}

// ---------------------------------------------------------------------------
// Fallback GEMM (ws too small for x16): reg-staged fp32 path.
// ---------------------------------------------------------------------------
__global__ __launch_bounds__(256) void score_gemm_f32(
    const float* __restrict__ A32p, const _Float16* __restrict__ Wt,
    const float* __restrict__ bias, const float* __restrict__ ctx,
    float* __restrict__ scores) {
    __shared__ _Float16 As[128 * 64];
    __shared__ _Float16 Bs[128 * 64];

    const int bid = blockIdx.x;
    const int bm = bid >> 3;
    const int bn = bid & 7;
    const int tid = threadIdx.x;
    const int lane = tid & 63;
    const int wid = tid >> 6;
    const int wm = wid >> 1;
    const int wn = wid & 1;

    const int c = tid & 7;
    const int r0 = tid >> 3;
    const int swz = (r0 & 7) << 3;
    const int wcol = (c * 8) ^ swz;

    float4 aF[4][2];
    int4   bR[4];

    #pragma unroll
    for (int i = 0; i < 4; ++i) {
        const int row = r0 + 32 * i;
        const float* p = A32p + (size_t)(bm * 128 + row) * KDIM + c * 8;
        aF[i][0] = *(const float4*)p;
        aF[i][1] = *(const float4*)(p + 4);
        bR[i] = *(const int4*)(Wt + (size_t)(bn * 128 + row) * KDIM + c * 8);
    }

    floatx4 acc[4][4] = {};

    for (int kt = 0; kt < KDIM / 64; ++kt) {
        __syncthreads();
        #pragma unroll
        for (int i = 0; i < 4; ++i) {
            const int row = r0 + 32 * i;
            half8 h;
            h[0] = (_Float16)aF[i][0].x; h[1] = (_Float16)aF[i][0].y;
            h[2] = (_Float16)aF[i][0].z; h[3] = (_Float16)aF[i][0].w;
            h[4] = (_Float16)aF[i][1].x; h[5] = (_Float16)aF[i][1].y;
            h[6] = (_Float16)aF[i][1].z; h[7] = (_Float16)aF[i][1].w;
            *(half8*)&As[row * 64 + wcol] = h;
            *(int4*)&Bs[row * 64 + wcol] = bR[i];
        }
        __syncthreads();

        if (kt + 1 < KDIM / 64) {
            #pragma unroll
            for (int i = 0; i < 4; ++i) {
                const int row = r0 + 32 * i;
                const float* p = A32p + (size_t)(bm * 128 + row) * KDIM + (kt + 1) * 64 + c * 8;
                aF[i][0] = *(const float4*)p;
                aF[i][1] = *(const float4*)(p + 4);
                bR[i] = *(const int4*)(Wt + (size_t)(bn * 128 + row) * KDIM + (kt + 1) * 64 + c * 8);
            }
        }

        #pragma unroll
        for (int s = 0; s < 2; ++s) {
            half8 afr[4], bfr[4];
            const int colr = s * 32 + (lane >> 4) * 8;
            #pragma unroll
            for (int m = 0; m < 4; ++m) {
                const int row = wm * 64 + m * 16 + (lane & 15);
                afr[m] = *(const half8*)&As[row * 64 + (colr ^ ((row & 7) << 3))];
            }
            #pragma unroll
            for (int n = 0; n < 4; ++n) {
                const int row = wn * 64 + n * 16 + (lane & 15);
                bfr[n] = *(const half8*)&Bs[row * 64 + (colr ^ ((row & 7) << 3))];
            }
            #pragma unroll
            for (int m = 0; m < 4; ++m)
                #pragma unroll
                for (int n = 0; n < 4; ++n)
                    acc[m][n] = __builtin_amdgcn_mfma_f32_16x16x32_f16(
                        afr[m], bfr[n], acc[m][n], 0, 0, 0);
        }
    }

    float bv[4], cv[4];
    #pragma unroll
    for (int n = 0; n < 4; ++n) {
        const int col = bn * 128 + wn * 64 + n * 16 + (lane & 15);
        bv[n] = bias[col];
        cv[n] = ctx[col];
    }
    #pragma unroll
    for (int m = 0; m < 4; ++m) {
        #pragma unroll
        for (int j = 0; j < 4; ++j) {
            float partial = 0.0f;
            #pragma unroll
            for (int n = 0; n < 4; ++n) {
                const float v = acc[m][n][j] + bv[n];
                const float e = __expf(2.0f * v);
                const float t = 1.0f - 2.0f * __builtin_amdgcn_rcpf(e + 1.0f);
                partial += t * cv[n];
            }
            #pragma unroll
            for (int off = 1; off < 16; off <<= 1)
                partial += __shfl_xor(partial, off, 64);
            if ((lane & 15) == 0) {
                const int rowg = bm * 128 + wm * 64 + m * 16 + (lane >> 4) * 4 + j;
                atomicAdd(&scores[rowg], partial);
            }
        }
    }
}

// ---------------------------------------------------------------------------
// Kernel 4: softmax over seq dim per batch. 32 blocks x 256 threads.
// ---------------------------------------------------------------------------
__global__ void softmax_kernel(const float* __restrict__ scores,
                               float* __restrict__ weights) {
    const int bb = blockIdx.x;
    const int tid = threadIdx.x;
    const float* s = scores + (size_t)bb * SEQ;
    float* w = weights + (size_t)bb * SEQ;

    __shared__ float red[8];

    float v[8];
    float mx = -1e30f;
    #pragma unroll
    for (int i = 0; i < 8; ++i) {
        v[i] = s[tid + i * 256];
        mx = fmaxf(mx, v[i]);
    }
    #pragma unroll
    for (int off = 1; off < 64; off <<= 1)
        mx = fmaxf(mx, __shfl_xor(mx, off, 64));
    const int wv = tid >> 6;
    if ((tid & 63) == 0) red[wv] = mx;
    __syncthreads();
    mx = fmaxf(fmaxf(red[0], red[1]), fmaxf(red[2], red[3]));

    float sum = 0.0f;
    #pragma unroll
    for (int i = 0; i < 8; ++i) {
        v[i] = __expf(v[i] - mx);
        sum += v[i];
    }
    #pragma unroll
    for (int off = 1; off < 64; off <<= 1)
        sum += __shfl_xor(sum, off, 64);
    if ((tid & 63) == 0) red[4 + wv] = sum;
    __syncthreads();
    sum = red[4] + red[5] + red[6] + red[7];
    const float inv = 1.0f / sum;
    #pragma unroll
    for (int i = 0; i < 8; ++i)
        w[tid + i * 256] = v[i] * inv;
}

// ---------------------------------------------------------------------------
// Kernel 5: weighted pooling (fp32 fallback).
// ---------------------------------------------------------------------------
__global__ __launch_bounds__(256) void pool_kernel(const float* __restrict__ x,
                                                   const float* __restrict__ weights,
                                                   float* __restrict__ out) {
    const int bb = blockIdx.x >> 4;
    const int sc = blockIdx.x & 15;
    const int tid = threadIdx.x;

    const float4* xb = (const float4*)(x + (size_t)bb * SEQ * EMBED) +
                       (size_t)(sc * 128) * (EMBED / 4) + tid;
    const float* wb = weights + (size_t)bb * SEQ + sc * 128;

    float ax = 0.f, ay = 0.f, az = 0.f, aw = 0.f;
    #pragma unroll 4
    for (int s = 0; s < 128; ++s) {
        const float wgt = wb[s];
        const float4 xv = xb[(size_t)s * (EMBED / 4)];
        ax += wgt * xv.x; ay += wgt * xv.y; az += wgt * xv.z; aw += wgt * xv.w;
    }
    float* o = out + (size_t)bb * EMBED + tid * 4;
    atomicAdd(o + 0, ax);
    atomicAdd(o + 1, ay);
    atomicAdd(o + 2, az);
    atomicAdd(o + 3, aw);
}

// ---------------------------------------------------------------------------
// Kernel 5b: weighted pooling (fp16 x16) — halves the read bytes.
// ---------------------------------------------------------------------------
__global__ __launch_bounds__(256) void pool16_kernel(const _Float16* __restrict__ x16,
                                                     const float* __restrict__ weights,
                                                     float* __restrict__ out) {
    const int bb = blockIdx.x >> 4;
    const int sc = blockIdx.x & 15;
    const int tid = threadIdx.x;

    const _Float16* xb = x16 + (size_t)bb * SEQ * EMBED +
                         (size_t)(sc * 128) * EMBED + tid * 4;
    const float* wb = weights + (size_t)bb * SEQ + sc * 128;

    float ax = 0.f, ay = 0.f, az = 0.f, aw = 0.f;
    #pragma unroll 4
    for (int s = 0; s < 128; ++s) {
        const float wgt = wb[s];
        const half4 h = *(const half4*)(xb + (size_t)s * EMBED);
        ax += wgt * (float)h[0]; ay += wgt * (float)h[1];
        az += wgt * (float)h[2]; aw += wgt * (float)h[3];
    }
    float* o = out + (size_t)bb * EMBED + tid * 4;
    atomicAdd(o + 0, ax);
    atomicAdd(o + 1, ay);
    atomicAdd(o + 2, az);
    atomicAdd(o + 3, aw);
}

// ---------------------------------------------------------------------------
extern "C" void kernel_launch(void* const* d_in, const int* in_sizes, int n_in,
                              void* d_out, int out_size, void* d_ws, size_t ws_size,
                              hipStream_t stream) {
    const float* x   = (const float*)d_in[0];
    const float* W   = (const float*)d_in[1];
    const float* b   = (const float*)d_in[2];
    const float* ctx = (const float*)d_in[3];
    float* out = (float*)d_out;

    char* ws = (char*)d_ws;
    _Float16* Wt      = (_Float16*)ws;                               // 2 MB
    float*    scores  = (float*)(ws + (2u << 20));                   // 256 KB
    float*    weights = (float*)(ws + (2u << 20) + (256u << 10));    // 256 KB
    _Float16* x16     = (_Float16*)(ws + (4u << 20));                // 128 MB

    const size_t need = (4ull << 20) + ((size_t)M_TOT * KDIM * 2);
    const bool fast = ws_size >= need;

    hipLaunchKernelGGL(transpose_w_kernel, dim3(32, 32), dim3(32, 8), 0, stream, W, Wt);
    hipLaunchKernelGGL(zero_kernel, dim3(M_TOT / 256), dim3(256), 0, stream, scores, out);

    if (fast) {
        hipLaunchKernelGGL(cvt_x_kernel, dim3(4096), dim3(256), 0, stream, x, x16);
        hipLaunchKernelGGL(score_gemm8, dim3(4096), dim3(256), 0, stream,
                           x16, Wt, b, ctx, scores);
    } else {
        hipLaunchKernelGGL(score_gemm_f32, dim3(4096), dim3(256), 0, stream,
                           x, Wt, b, ctx, scores);
    }

    hipLaunchKernelGGL(softmax_kernel, dim3(BATCH), dim3(256), 0, stream, scores, weights);

    if (fast) {
        hipLaunchKernelGGL(pool16_kernel, dim3(BATCH * 16), dim3(256), 0, stream,
                           x16, weights, out);
    } else {
        hipLaunchKernelGGL(pool_kernel, dim3(BATCH * 16), dim3(256), 0, stream,
                           x, weights, out);
    }
}

// Round 11
// 287.435 us; speedup vs baseline: 1.2515x; 1.0076x over previous
//
#include <hip/hip_runtime.h>
#include <hip/hip_bf16.h>

typedef _Float16 half8 __attribute__((ext_vector_type(8)));
typedef _Float16 half4 __attribute__((ext_vector_type(4)));
typedef float floatx4 __attribute__((ext_vector_type(4)));

#define EMBED 1024
#define SEQ   2048
#define BATCH 32
#define M_TOT (BATCH * SEQ)   // 65536 rows
#define KDIM  1024
#define NDIM  1024

// async global->LDS, 16B per lane, dest = wave-uniform base + lane*16
#define GLOAD16(g, l) __builtin_amdgcn_global_load_lds(                      \
    (const __attribute__((address_space(1))) void*)(g),                      \
    (__attribute__((address_space(3))) void*)(l), 16, 0, 0)

// ---------------------------------------------------------------------------
// Kernel 1 (slow path only): transpose + convert W[K][N] fp32 -> Wt[N][K] fp16
// ---------------------------------------------------------------------------
__global__ void transpose_w_kernel(const float* __restrict__ W,
                                   _Float16* __restrict__ Wt) {
    __shared__ float t[32][33];
    const int kt = blockIdx.x * 32;
    const int nt = blockIdx.y * 32;
    #pragma unroll
    for (int i = 0; i < 4; ++i)
        t[threadIdx.y + 8 * i][threadIdx.x] =
            W[(size_t)(kt + threadIdx.y + 8 * i) * NDIM + nt + threadIdx.x];
    __syncthreads();
    #pragma unroll
    for (int i = 0; i < 4; ++i)
        Wt[(size_t)(nt + threadIdx.y + 8 * i) * KDIM + kt + threadIdx.x] =
            (_Float16)t[threadIdx.x][threadIdx.y + 8 * i];
}

// ---------------------------------------------------------------------------
// Kernel 1b (fast path): pack W[K][N] fp32 -> fragment-order fp16 buffer
// Bp[bn][kt][wn][nf][lane][8]: element (col = bn*128+wn*64+nf*16+(lane&15),
// k = kt*32+(lane>>4)*8+j).  A wave's B-frag load becomes one coalesced
// 1 KB global_load_dwordx4 (L2-resident, 2 MB total).
// ---------------------------------------------------------------------------
__global__ __launch_bounds__(256) void pack_w_kernel(const float* __restrict__ W,
                                                     _Float16* __restrict__ Bp) {
    const int flat = blockIdx.x * 256 + threadIdx.x;   // 131072 tuples
    int t = flat;
    const int lane = t & 63; t >>= 6;
    const int nf   = t & 3;  t >>= 2;
    const int wn   = t & 1;  t >>= 1;
    const int kt   = t & 31; t >>= 5;
    const int bn   = t;      // 0..7
    const int col = bn * 128 + wn * 64 + nf * 16 + (lane & 15);
    const int k0  = kt * 32 + (lane >> 4) * 8;
    half8 h;
    #pragma unroll
    for (int j = 0; j < 8; ++j)
        h[j] = (_Float16)W[(size_t)(k0 + j) * NDIM + col];
    *(half8*)(Bp + (size_t)flat * 8) = h;
}

// ---------------------------------------------------------------------------
// Kernel 2: zero scores + out
// ---------------------------------------------------------------------------
__global__ void zero_kernel(float* __restrict__ scores, float* __restrict__ out) {
    const int i = blockIdx.x * 256 + threadIdx.x;
    if (i < M_TOT) scores[i] = 0.0f;
    if (i < BATCH * EMBED) out[i] = 0.0f;
}

// ---------------------------------------------------------------------------
// Kernel 2b: convert x fp32 -> fp16 (64M elements)
// ---------------------------------------------------------------------------
__global__ __launch_bounds__(256) void cvt_x_kernel(const float* __restrict__ x,
                                                    _Float16* __restrict__ x16) {
    const size_t stride = (size_t)gridDim.x * 256 * 8;
    for (size_t i = ((size_t)blockIdx.x * 256 + threadIdx.x) * 8;
         i < (size_t)M_TOT * KDIM; i += stride) {
        const float4 a = *(const float4*)(x + i);
        const float4 b = *(const float4*)(x + i + 4);
        half8 h;
        h[0] = (_Float16)a.x; h[1] = (_Float16)a.y; h[2] = (_Float16)a.z; h[3] = (_Float16)a.w;
        h[4] = (_Float16)b.x; h[5] = (_Float16)b.y; h[6] = (_Float16)b.z; h[7] = (_Float16)b.w;
        *(half8*)(x16 + i) = h;
    }
}

// ---------------------------------------------------------------------------
// Kernel 3: fused scores GEMM — r10 structure, B MOVED OFF LDS.
// BM=128, BN=128, BK=32, 256 threads (2x2 waves, 64x64 wave-tile),
// mfma_f32_16x16x32_f16.
//   A: gload_lds(16B) into double-buffered LDS, r10's conflict-free swizzle
//      (verified: SQ_LDS_BANK_CONFLICT = 0).
//   B: per-K-step coalesced register loads from the packed L2-resident Bp
//      (4 x 1KB dwordx4 per wave), source-level double-buffered; the
//      end-of-iter __syncthreads vmcnt-drain gives them the MFMA cluster
//      (~300-600 cy) to cover ~200 cy L2 latency.
// LDS traffic per block-K-step drops 48 KB -> 24 KB (the audited binder).
// ---------------------------------------------------------------------------
__global__ __launch_bounds__(256, 4) void score_gemm9(
    const _Float16* __restrict__ x16, const _Float16* __restrict__ Bp,
    const float* __restrict__ bias, const float* __restrict__ ctx,
    float* __restrict__ scores) {
    __shared__ _Float16 As[2][128 * 32];

    // XCD-aware chunk swizzle (4096 blocks, 8 XCDs, bijective)
    const int nb = ((blockIdx.x & 7) << 9) | (blockIdx.x >> 3);
    const int bm = nb >> 3;       // 512 row tiles, contiguous per XCD
    const int bn = nb & 7;        // 8 col tiles, innermost per XCD
    const int tid = threadIdx.x;
    const int lane = tid & 63;
    const int wid = tid >> 6;
    const int wm = wid >> 1;
    const int wn = wid & 1;

    // A staging: instr j covers rows j*16..j*16+15; lane l -> row j*16+(l>>2),
    // LDS slot l&3 linear; global slot pre-swizzled g = (l&3) ^ ((l>>3)&3).
    const int jA0 = wid;                            // 1 A-instr per wave... (see below)
    const int lrow = lane >> 2;                     // 0..15
    const int gslot = (lane & 3) ^ ((lane >> 3) & 3);
    const int gcol = gslot * 8;                     // halves

    const _Float16* Ab = x16 + (size_t)(bm * 128) * KDIM;

    floatx4 acc[4][4] = {};

    // frag read: row = base + frow, logical slot s = lane>>4,
    // physical p = s ^ ((row>>1)&3) = s ^ ((frow>>1)&3)
    const int frow = lane & 15;
    const int fslot = ((lane >> 4) ^ ((frow >> 1) & 3)) * 8;   // halves

    // A: 8 instrs per block (128 rows / 16), wave w owns instrs {w, w+4}
    #define STAGE(buf, kt)                                                        \
        {                                                                         \
            const int kc = (kt) * 32 + gcol;                                      \
            _Pragma("unroll")                                                     \
            for (int i = 0; i < 2; ++i) {                                         \
                const int j = jA0 + i * 4;                                        \
                GLOAD16(Ab + (size_t)(j * 16 + lrow) * KDIM + kc, &As[buf][j * 512]); \
            }                                                                     \
        }

    // B: packed frag loads, idx(int4) = (((bn*32+kt)*2+wn)*4+nf)*64 + lane
    const int4* Bp4 = (const int4*)Bp;
    #define BLOAD(dst, kt)                                                        \
        {                                                                         \
            const int4* p = Bp4 + ((((size_t)bn * 32 + (kt)) * 2 + wn) * 4) * 64 + lane; \
            dst[0] = p[0]; dst[1] = p[64]; dst[2] = p[128]; dst[3] = p[192];      \
        }

    int4 Bcur[4], Bnext[4];

    STAGE(0, 0);
    BLOAD(Bcur, 0);
    __syncthreads();   // drains vmcnt(0): As buf0 + Bcur ready

    for (int kt = 0; kt < KDIM / 32; ++kt) {
        const int cur = kt & 1;
        if (kt + 1 < KDIM / 32) {
            STAGE(cur ^ 1, kt + 1);    // async LDS stage, in flight under compute
            BLOAD(Bnext, kt + 1);      // register prefetch from L2
        }

        half8 afr[4];
        #pragma unroll
        for (int m = 0; m < 4; ++m)
            afr[m] = *(const half8*)&As[cur][(wm * 64 + m * 16 + frow) * 32 + fslot];

        #pragma unroll
        for (int m = 0; m < 4; ++m)
            #pragma unroll
            for (int n = 0; n < 4; ++n)
                acc[m][n] = __builtin_amdgcn_mfma_f32_16x16x32_f16(
                    afr[m], *(const half8*)&Bcur[n], acc[m][n], 0, 0, 0);

        __syncthreads();   // drains STAGE + BLOAD; orders buf reuse
        #pragma unroll
        for (int n = 0; n < 4; ++n) Bcur[n] = Bnext[n];
    }
    #undef BLOAD
    #undef STAGE

    // ---- epilogue: fast tanh + ctx dot + 16-lane reduce + atomic ----
    float bv[4], cv[4];
    #pragma unroll
    for (int n = 0; n < 4; ++n) {
        const int col = bn * 128 + wn * 64 + n * 16 + (lane & 15);
        bv[n] = bias[col];
        cv[n] = ctx[col];
    }
    #pragma unroll
    for (int m = 0; m < 4; ++m) {
        #pragma unroll
        for (int j = 0; j < 4; ++j) {
            float partial = 0.0f;
            #pragma unroll
            for (int n = 0; n < 4; ++n) {
                const float v = acc[m][n][j] + bv[n];
                const float e = __expf(2.0f * v);          // tanh(v)=1-2/(e^{2v}+1)
                const float t = 1.0f - 2.0f * __builtin_amdgcn_rcpf(e + 1.0f);
                partial += t * cv[n];
            }
            #pragma unroll
            for (int off = 1; off < 16; off <<= 1)
                partial += __shfl_xor(partial, off, 64);
            if ((lane & 15) == 0) {
                const int rowg = bm * 128 + wm * 64 + m * 16 + (lane >> 4) * 4 + j;
                atomicAdd(&scores[rowg], partial);
            }
        }
    }
}

// ---------------------------------------------------------------------------
// Fallback GEMM (ws too small for x16): reg-staged fp32 path.
// ---------------------------------------------------------------------------
__global__ __launch_bounds__(256) void score_gemm_f32(
    const float* __restrict__ A32p, const _Float16* __restrict__ Wt,
    const float* __restrict__ bias, const float* __restrict__ ctx,
    float* __restrict__ scores) {
    __shared__ _Float16 As[128 * 64];
    __shared__ _Float16 Bs[128 * 64];

    const int bid = blockIdx.x;
    const int bm = bid >> 3;
    const int bn = bid & 7;
    const int tid = threadIdx.x;
    const int lane = tid & 63;
    const int wid = tid >> 6;
    const int wm = wid >> 1;
    const int wn = wid & 1;

    const int c = tid & 7;
    const int r0 = tid >> 3;
    const int swz = (r0 & 7) << 3;
    const int wcol = (c * 8) ^ swz;

    float4 aF[4][2];
    int4   bR[4];

    #pragma unroll
    for (int i = 0; i < 4; ++i) {
        const int row = r0 + 32 * i;
        const float* p = A32p + (size_t)(bm * 128 + row) * KDIM + c * 8;
        aF[i][0] = *(const float4*)p;
        aF[i][1] = *(const float4*)(p + 4);
        bR[i] = *(const int4*)(Wt + (size_t)(bn * 128 + row) * KDIM + c * 8);
    }

    floatx4 acc[4][4] = {};

    for (int kt = 0; kt < KDIM / 64; ++kt) {
        __syncthreads();
        #pragma unroll
        for (int i = 0; i < 4; ++i) {
            const int row = r0 + 32 * i;
            half8 h;
            h[0] = (_Float16)aF[i][0].x; h[1] = (_Float16)aF[i][0].y;
            h[2] = (_Float16)aF[i][0].z; h[3] = (_Float16)aF[i][0].w;
            h[4] = (_Float16)aF[i][1].x; h[5] = (_Float16)aF[i][1].y;
            h[6] = (_Float16)aF[i][1].z; h[7] = (_Float16)aF[i][1].w;
            *(half8*)&As[row * 64 + wcol] = h;
            *(int4*)&Bs[row * 64 + wcol] = bR[i];
        }
        __syncthreads();

        if (kt + 1 < KDIM / 64) {
            #pragma unroll
            for (int i = 0; i < 4; ++i) {
                const int row = r0 + 32 * i;
                const float* p = A32p + (size_t)(bm * 128 + row) * KDIM + (kt + 1) * 64 + c * 8;
                aF[i][0] = *(const float4*)p;
                aF[i][1] = *(const float4*)(p + 4);
                bR[i] = *(const int4*)(Wt + (size_t)(bn * 128 + row) * KDIM + (kt + 1) * 64 + c * 8);
            }
        }

        #pragma unroll
        for (int s = 0; s < 2; ++s) {
            half8 afr[4], bfr[4];
            const int colr = s * 32 + (lane >> 4) * 8;
            #pragma unroll
            for (int m = 0; m < 4; ++m) {
                const int row = wm * 64 + m * 16 + (lane & 15);
                afr[m] = *(const half8*)&As[row * 64 + (colr ^ ((row & 7) << 3))];
            }
            #pragma unroll
            for (int n = 0; n < 4; ++n) {
                const int row = wn * 64 + n * 16 + (lane & 15);
                bfr[n] = *(const half8*)&Bs[row * 64 + (colr ^ ((row & 7) << 3))];
            }
            #pragma unroll
            for (int m = 0; m < 4; ++m)
                #pragma unroll
                for (int n = 0; n < 4; ++n)
                    acc[m][n] = __builtin_amdgcn_mfma_f32_16x16x32_f16(
                        afr[m], bfr[n], acc[m][n], 0, 0, 0);
        }
    }

    float bv[4], cv[4];
    #pragma unroll
    for (int n = 0; n < 4; ++n) {
        const int col = bn * 128 + wn * 64 + n * 16 + (lane & 15);
        bv[n] = bias[col];
        cv[n] = ctx[col];
    }
    #pragma unroll
    for (int m = 0; m < 4; ++m) {
        #pragma unroll
        for (int j = 0; j < 4; ++j) {
            float partial = 0.0f;
            #pragma unroll
            for (int n = 0; n < 4; ++n) {
                const float v = acc[m][n][j] + bv[n];
                const float e = __expf(2.0f * v);
                const float t = 1.0f - 2.0f * __builtin_amdgcn_rcpf(e + 1.0f);
                partial += t * cv[n];
            }
            #pragma unroll
            for (int off = 1; off < 16; off <<= 1)
                partial += __shfl_xor(partial, off, 64);
            if ((lane & 15) == 0) {
                const int rowg = bm * 128 + wm * 64 + m * 16 + (lane >> 4) * 4 + j;
                atomicAdd(&scores[rowg], partial);
            }
        }
    }
}

// ---------------------------------------------------------------------------
// Kernel 4: softmax over seq dim per batch. 32 blocks x 256 threads.
// ---------------------------------------------------------------------------
__global__ void softmax_kernel(const float* __restrict__ scores,
                               float* __restrict__ weights) {
    const int bb = blockIdx.x;
    const int tid = threadIdx.x;
    const float* s = scores + (size_t)bb * SEQ;
    float* w = weights + (size_t)bb * SEQ;

    __shared__ float red[8];

    float v[8];
    float mx = -1e30f;
    #pragma unroll
    for (int i = 0; i < 8; ++i) {
        v[i] = s[tid + i * 256];
        mx = fmaxf(mx, v[i]);
    }
    #pragma unroll
    for (int off = 1; off < 64; off <<= 1)
        mx = fmaxf(mx, __shfl_xor(mx, off, 64));
    const int wv = tid >> 6;
    if ((tid & 63) == 0) red[wv] = mx;
    __syncthreads();
    mx = fmaxf(fmaxf(red[0], red[1]), fmaxf(red[2], red[3]));

    float sum = 0.0f;
    #pragma unroll
    for (int i = 0; i < 8; ++i) {
        v[i] = __expf(v[i] - mx);
        sum += v[i];
    }
    #pragma unroll
    for (int off = 1; off < 64; off <<= 1)
        sum += __shfl_xor(sum, off, 64);
    if ((tid & 63) == 0) red[4 + wv] = sum;
    __syncthreads();
    sum = red[4] + red[5] + red[6] + red[7];
    const float inv = 1.0f / sum;
    #pragma unroll
    for (int i = 0; i < 8; ++i)
        w[tid + i * 256] = v[i] * inv;
}

// ---------------------------------------------------------------------------
// Kernel 5: weighted pooling (fp32 fallback).
// ---------------------------------------------------------------------------
__global__ __launch_bounds__(256) void pool_kernel(const float* __restrict__ x,
                                                   const float* __restrict__ weights,
                                                   float* __restrict__ out) {
    const int bb = blockIdx.x >> 4;
    const int sc = blockIdx.x & 15;
    const int tid = threadIdx.x;

    const float4* xb = (const float4*)(x + (size_t)bb * SEQ * EMBED) +
                       (size_t)(sc * 128) * (EMBED / 4) + tid;
    const float* wb = weights + (size_t)bb * SEQ + sc * 128;

    float ax = 0.f, ay = 0.f, az = 0.f, aw = 0.f;
    #pragma unroll 4
    for (int s = 0; s < 128; ++s) {
        const float wgt = wb[s];
        const float4 xv = xb[(size_t)s * (EMBED / 4)];
        ax += wgt * xv.x; ay += wgt * xv.y; az += wgt * xv.z; aw += wgt * xv.w;
    }
    float* o = out + (size_t)bb * EMBED + tid * 4;
    atomicAdd(o + 0, ax);
    atomicAdd(o + 1, ay);
    atomicAdd(o + 2, az);
    atomicAdd(o + 3, aw);
}

// ---------------------------------------------------------------------------
// Kernel 5b: weighted pooling (fp16 x16) — halves the read bytes.
// ---------------------------------------------------------------------------
__global__ __launch_bounds__(256) void pool16_kernel(const _Float16* __restrict__ x16,
                                                     const float* __restrict__ weights,
                                                     float* __restrict__ out) {
    const int bb = blockIdx.x >> 4;
    const int sc = blockIdx.x & 15;
    const int tid = threadIdx.x;

    const _Float16* xb = x16 + (size_t)bb * SEQ * EMBED +
                         (size_t)(sc * 128) * EMBED + tid * 4;
    const float* wb = weights + (size_t)bb * SEQ + sc * 128;

    float ax = 0.f, ay = 0.f, az = 0.f, aw = 0.f;
    #pragma unroll 4
    for (int s = 0; s < 128; ++s) {
        const float wgt = wb[s];
        const half4 h = *(const half4*)(xb + (size_t)s * EMBED);
        ax += wgt * (float)h[0]; ay += wgt * (float)h[1];
        az += wgt * (float)h[2]; aw += wgt * (float)h[3];
    }
    float* o = out + (size_t)bb * EMBED + tid * 4;
    atomicAdd(o + 0, ax);
    atomicAdd(o + 1, ay);
    atomicAdd(o + 2, az);
    atomicAdd(o + 3, aw);
}

// ---------------------------------------------------------------------------
extern "C" void kernel_launch(void* const* d_in, const int* in_sizes, int n_in,
                              void* d_out, int out_size, void* d_ws, size_t ws_size,
                              hipStream_t stream) {
    const float* x   = (const float*)d_in[0];
    const float* W   = (const float*)d_in[1];
    const float* b   = (const float*)d_in[2];
    const float* ctx = (const float*)d_in[3];
    float* out = (float*)d_out;

    char* ws = (char*)d_ws;
    // offset 0 holds Bp (fast path) OR Wt (slow path) — paths are disjoint.
    _Float16* Bp      = (_Float16*)ws;                               // 2 MB
    _Float16* Wt      = (_Float16*)ws;                               // 2 MB
    float*    scores  = (float*)(ws + (2u << 20));                   // 256 KB
    float*    weights = (float*)(ws + (2u << 20) + (256u << 10));    // 256 KB
    _Float16* x16     = (_Float16*)(ws + (4u << 20));                // 128 MB

    const size_t need = (4ull << 20) + ((size_t)M_TOT * KDIM * 2);
    const bool fast = ws_size >= need;

    hipLaunchKernelGGL(zero_kernel, dim3(M_TOT / 256), dim3(256), 0, stream, scores, out);

    if (fast) {
        hipLaunchKernelGGL(pack_w_kernel, dim3(512), dim3(256), 0, stream, W, Bp);
        hipLaunchKernelGGL(cvt_x_kernel, dim3(4096), dim3(256), 0, stream, x, x16);
        hipLaunchKernelGGL(score_gemm9, dim3(4096), dim3(256), 0, stream,
                           x16, Bp, b, ctx, scores);
    } else {
        hipLaunchKernelGGL(transpose_w_kernel, dim3(32, 32), dim3(32, 8), 0, stream, W, Wt);
        hipLaunchKernelGGL(score_gemm_f32, dim3(4096), dim3(256), 0, stream,
                           x, Wt, b, ctx, scores);
    }

    hipLaunchKernelGGL(softmax_kernel, dim3(BATCH), dim3(256), 0, stream, scores, weights);

    if (fast) {
        hipLaunchKernelGGL(pool16_kernel, dim3(BATCH * 16), dim3(256), 0, stream,
                           x16, weights, out);
    } else {
        hipLaunchKernelGGL(pool_kernel, dim3(BATCH * 16), dim3(256), 0, stream,
                           x, weights, out);
    }
}